// Round 1
// baseline (6387.654 us; speedup 1.0000x reference)
//
#include <hip/hip_runtime.h>

// GraphSAGE fused pipeline, fp32 baseline.
// Layout of ws (floats): agg[N*128] | y[N*128] | skip[N*128] | x1[N*128] |
//                        cnt[N] | colsum[128] | colsq[128] | scale[128] | shift[128]
// ~205 MB total.

#define F   128
#define FH  64
#define EPS 1e-5f

constexpr int TILE_R = 64;

// ---------------- edge scatter: agg[dst] += x[src], cnt[dst] += 1 ----------------
__global__ __launch_bounds__(256) void scatter_kernel(
    const float* __restrict__ xin, const int* __restrict__ src,
    const int* __restrict__ dst, float* __restrict__ agg,
    float* __restrict__ cnt, int E, int do_cnt)
{
    int t = blockIdx.x * 256 + threadIdx.x;
    int e = t >> 5;            // 32 threads per edge
    int lane = t & 31;         // each thread: 4 consecutive features
    if (e >= E) return;
    int s = src[e];
    int d = dst[e];
    float4 v = reinterpret_cast<const float4*>(xin)[s * 32 + lane];
    float* dp = agg + (size_t)d * F + lane * 4;
    unsafeAtomicAdd(dp + 0, v.x);
    unsafeAtomicAdd(dp + 1, v.y);
    unsafeAtomicAdd(dp + 2, v.z);
    unsafeAtomicAdd(dp + 3, v.w);
    if (do_cnt && lane == 0) unsafeAtomicAdd(cnt + d, 1.0f);
}

// ---------------- fused: y = (agg/cnt)@Wl + x@Wr + bl ; skip = relu(x@sw1+sb1)@sw2+sb2
//                  plus column sum / sumsq of y for BatchNorm -----------------------
__global__ __launch_bounds__(256) void fused_gemm_kernel(
    const float* __restrict__ xin, const float* __restrict__ agg,
    const float* __restrict__ cnt,
    const float* __restrict__ Wl, const float* __restrict__ bl,
    const float* __restrict__ Wr,
    const float* __restrict__ sw1, const float* __restrict__ sb1,
    const float* __restrict__ sw2, const float* __restrict__ sb2,
    float* __restrict__ y, float* __restrict__ skip,
    float* __restrict__ colsum, float* __restrict__ colsq, int n)
{
    __shared__ float xs[TILE_R][F];    // 32 KB
    __shared__ float as_[TILE_R][F];   // 32 KB (reused as h buffer in phase 3/4)
    const int tid = threadIdx.x;
    const int r0 = blockIdx.x * TILE_R;

    // ---- stage x tile and normalized agg tile into LDS ----
    for (int i = tid; i < TILE_R * (F / 4); i += 256) {
        int r = i >> 5;        // /32 float4 per row
        int c4 = i & 31;
        int row = r0 + r;
        float4 v = make_float4(0.f, 0.f, 0.f, 0.f);
        float4 a = make_float4(0.f, 0.f, 0.f, 0.f);
        if (row < n) {
            v = reinterpret_cast<const float4*>(xin)[row * 32 + c4];
            a = reinterpret_cast<const float4*>(agg)[row * 32 + c4];
            float inv = 1.0f / fmaxf(cnt[row], 1.0f);
            a.x *= inv; a.y *= inv; a.z *= inv; a.w *= inv;
        }
        reinterpret_cast<float4*>(&xs[r][0])[c4] = v;
        reinterpret_cast<float4*>(&as_[r][0])[c4] = a;
    }
    __syncthreads();

    // ---- phase 2: y tile. thread -> col j, half rh; 32 rows each ----
    const int j = tid & 127;
    const int rh = tid >> 7;       // 0..1
    const int rbase = rh * 32;
    float acc[32];
#pragma unroll
    for (int r = 0; r < 32; ++r) acc[r] = 0.f;
    for (int k = 0; k < F; k += 4) {
        float wl0 = Wl[(k + 0) * F + j], wl1 = Wl[(k + 1) * F + j],
              wl2 = Wl[(k + 2) * F + j], wl3 = Wl[(k + 3) * F + j];
        float wr0 = Wr[(k + 0) * F + j], wr1 = Wr[(k + 1) * F + j],
              wr2 = Wr[(k + 2) * F + j], wr3 = Wr[(k + 3) * F + j];
#pragma unroll
        for (int r = 0; r < 32; ++r) {
            const float4 xa = *reinterpret_cast<const float4*>(&xs[rbase + r][k]);
            const float4 aa = *reinterpret_cast<const float4*>(&as_[rbase + r][k]);
            acc[r] += aa.x * wl0 + aa.y * wl1 + aa.z * wl2 + aa.w * wl3
                    + xa.x * wr0 + xa.y * wr1 + xa.z * wr2 + xa.w * wr3;
        }
    }
    {
        const float bias = bl[j];
        float psum = 0.f, psq = 0.f;
#pragma unroll
        for (int r = 0; r < 32; ++r) {
            int row = r0 + rbase + r;
            if (row < n) {
                float v = acc[r] + bias;
                y[(size_t)row * F + j] = v;
                psum += v; psq += v * v;
            }
        }
        unsafeAtomicAdd(colsum + j, psum);
        unsafeAtomicAdd(colsq + j, psq);
    }

    // ---- phase 3: h = relu(x@sw1 + sb1), [TILE_R][FH] ----
    const int jh = tid & 63;
    const int rq = tid >> 6;       // 0..3
    const int rb2 = rq * 16;
    float hacc[16];
#pragma unroll
    for (int r = 0; r < 16; ++r) hacc[r] = 0.f;
    for (int k = 0; k < F; k += 4) {
        float w0 = sw1[(k + 0) * FH + jh], w1 = sw1[(k + 1) * FH + jh],
              w2 = sw1[(k + 2) * FH + jh], w3 = sw1[(k + 3) * FH + jh];
#pragma unroll
        for (int r = 0; r < 16; ++r) {
            const float4 xa = *reinterpret_cast<const float4*>(&xs[rb2 + r][k]);
            hacc[r] += xa.x * w0 + xa.y * w1 + xa.z * w2 + xa.w * w3;
        }
    }
    const float hb = sb1[jh];
    __syncthreads();               // all phase-2/3 reads of as_ complete
    float* hs = &as_[0][0];        // reuse as h[TILE_R][FH]
#pragma unroll
    for (int r = 0; r < 16; ++r)
        hs[(rb2 + r) * FH + jh] = fmaxf(hacc[r] + hb, 0.f);
    __syncthreads();

    // ---- phase 4: skip = h @ sw2 + sb2 ----
    float sacc[32];
#pragma unroll
    for (int r = 0; r < 32; ++r) sacc[r] = 0.f;
    for (int k = 0; k < FH; k += 4) {
        float w0 = sw2[(k + 0) * F + j], w1 = sw2[(k + 1) * F + j],
              w2 = sw2[(k + 2) * F + j], w3 = sw2[(k + 3) * F + j];
#pragma unroll
        for (int r = 0; r < 32; ++r) {
            const float4 ha = *reinterpret_cast<const float4*>(&hs[(rbase + r) * FH + k]);
            sacc[r] += ha.x * w0 + ha.y * w1 + ha.z * w2 + ha.w * w3;
        }
    }
    const float sb = sb2[j];
#pragma unroll
    for (int r = 0; r < 32; ++r) {
        int row = r0 + rbase + r;
        if (row < n) skip[(size_t)row * F + j] = sacc[r] + sb;
    }
}

// ---------------- BN stats -> scale/shift ----------------
__global__ void bn_finalize_kernel(const float* __restrict__ colsum,
                                   const float* __restrict__ colsq,
                                   const float* __restrict__ g,
                                   const float* __restrict__ beta,
                                   float* __restrict__ scale,
                                   float* __restrict__ shift, float invn)
{
    int j = threadIdx.x;
    float mu = colsum[j] * invn;
    float var = colsq[j] * invn - mu * mu;
    float rs = rsqrtf(var + EPS);
    float sc = rs * g[j];
    scale[j] = sc;
    shift[j] = beta[j] - mu * sc;
}

// ---------------- out = relu(y*scale + shift + skip) ----------------
__global__ __launch_bounds__(256) void apply_kernel(
    const float* __restrict__ y, const float* __restrict__ skip,
    const float* __restrict__ scale, const float* __restrict__ shift,
    float* __restrict__ out, int n4)
{
    int t = blockIdx.x * 256 + threadIdx.x;
    if (t >= n4) return;
    int j4 = t & 31;
    float4 v = reinterpret_cast<const float4*>(y)[t];
    float4 s = reinterpret_cast<const float4*>(skip)[t];
    float4 sc = reinterpret_cast<const float4*>(scale)[j4];
    float4 sh = reinterpret_cast<const float4*>(shift)[j4];
    float4 o;
    o.x = fmaxf(v.x * sc.x + sh.x + s.x, 0.f);
    o.y = fmaxf(v.y * sc.y + sh.y + s.y, 0.f);
    o.z = fmaxf(v.z * sc.z + sh.z + s.z, 0.f);
    o.w = fmaxf(v.w * sc.w + sh.w + s.w, 0.f);
    reinterpret_cast<float4*>(out)[t] = o;
}

extern "C" void kernel_launch(void* const* d_in, const int* in_sizes, int n_in,
                              void* d_out, int out_size, void* d_ws, size_t ws_size,
                              hipStream_t stream)
{
    const float* x    = (const float*)d_in[0];
    const int*   ei   = (const int*)d_in[1];   // [2,E] int32 (harness convention)
    const float* Wl1  = (const float*)d_in[2];
    const float* bl1  = (const float*)d_in[3];
    const float* Wr1  = (const float*)d_in[4];
    const float* Wl2  = (const float*)d_in[5];
    const float* bl2  = (const float*)d_in[6];
    const float* Wr2  = (const float*)d_in[7];
    const float* s1w1 = (const float*)d_in[8];
    const float* s1b1 = (const float*)d_in[9];
    const float* s1w2 = (const float*)d_in[10];
    const float* s1b2 = (const float*)d_in[11];
    const float* s2w1 = (const float*)d_in[12];
    const float* s2b1 = (const float*)d_in[13];
    const float* s2w2 = (const float*)d_in[14];
    const float* s2b2 = (const float*)d_in[15];
    const float* g1   = (const float*)d_in[16];
    const float* be1  = (const float*)d_in[17];
    const float* g2   = (const float*)d_in[18];
    const float* be2  = (const float*)d_in[19];

    const int n = in_sizes[0] / F;       // 100000
    const int E = in_sizes[1] / 2;       // 1600000
    const int* src = ei;
    const int* dst = ei + E;

    float* ws = (float*)d_ws;
    size_t off = 0;
    float* agg  = ws + off; off += (size_t)n * F;
    float* ybuf = ws + off; off += (size_t)n * F;
    float* sbuf = ws + off; off += (size_t)n * F;
    float* x1   = ws + off; off += (size_t)n * F;
    float* cnt  = ws + off; off += (size_t)n;
    float* csum = ws + off; off += F;
    float* csq  = ws + off; off += F;
    float* scl  = ws + off; off += F;
    float* shf  = ws + off; off += F;

    const int sblocks = (E * 32 + 255) / 256;
    const int gblocks = (n + TILE_R - 1) / TILE_R;
    const int n4 = n * (F / 4);
    const int ablocks = (n4 + 255) / 256;
    const float invn = 1.0f / (float)n;

    // ---- layer 1 ----
    hipMemsetAsync(agg, 0, (size_t)n * F * sizeof(float), stream);
    hipMemsetAsync(cnt, 0, (size_t)n * sizeof(float), stream);
    hipMemsetAsync(csum, 0, 2 * F * sizeof(float), stream);   // csum + csq
    scatter_kernel<<<sblocks, 256, 0, stream>>>(x, src, dst, agg, cnt, E, 1);
    fused_gemm_kernel<<<gblocks, 256, 0, stream>>>(x, agg, cnt, Wl1, bl1, Wr1,
        s1w1, s1b1, s1w2, s1b2, ybuf, sbuf, csum, csq, n);
    bn_finalize_kernel<<<1, F, 0, stream>>>(csum, csq, g1, be1, scl, shf, invn);
    apply_kernel<<<ablocks, 256, 0, stream>>>(ybuf, sbuf, scl, shf, x1, n4);

    // ---- layer 2 (cnt is identical; reuse) ----
    hipMemsetAsync(agg, 0, (size_t)n * F * sizeof(float), stream);
    hipMemsetAsync(csum, 0, 2 * F * sizeof(float), stream);
    scatter_kernel<<<sblocks, 256, 0, stream>>>(x1, src, dst, agg, nullptr, E, 0);
    fused_gemm_kernel<<<gblocks, 256, 0, stream>>>(x1, agg, cnt, Wl2, bl2, Wr2,
        s2w1, s2b1, s2w2, s2b2, ybuf, sbuf, csum, csq, n);
    bn_finalize_kernel<<<1, F, 0, stream>>>(csum, csq, g2, be2, scl, shf, invn);
    apply_kernel<<<ablocks, 256, 0, stream>>>(ybuf, sbuf, scl, shf, (float*)d_out, n4);
}

// Round 2
// 1320.742 us; speedup vs baseline: 4.8364x; 4.8364x over previous
//
#include <hip/hip_runtime.h>

// GraphSAGE fused pipeline, round 2: CSR gather aggregation (no fp atomics).
//
// ws layout (see kernel_launch): agg/skip[N*F] | y[N*F] | x1[N*F] | small fp vecs |
//                                deg[N] | start[N] | cursor[N] | incl[N] | bsum | boff | eid[E]

#define F   128
#define FH  64
#define EPS 1e-5f

constexpr int TILE_R = 64;

// ---------------- CSR build ----------------
__global__ __launch_bounds__(256) void deg_kernel(
    const int* __restrict__ dst, int* __restrict__ deg, int E)
{
    int t = blockIdx.x * 256 + threadIdx.x;
    if (t < E) atomicAdd(&deg[dst[t]], 1);
}

// per-block inclusive scan of 1024 elements
__global__ __launch_bounds__(1024) void scan1_kernel(
    const int* __restrict__ deg, int* __restrict__ incl,
    int* __restrict__ bsum, int n)
{
    __shared__ int s[1024];
    int t = threadIdx.x;
    int idx = blockIdx.x * 1024 + t;
    int v = (idx < n) ? deg[idx] : 0;
    s[t] = v;
    __syncthreads();
    for (int o = 1; o < 1024; o <<= 1) {
        int a = (t >= o) ? s[t - o] : 0;
        __syncthreads();
        s[t] += a;
        __syncthreads();
    }
    if (idx < n) incl[idx] = s[t];
    if (t == 1023) bsum[blockIdx.x] = s[t];
}

__global__ void scan2_kernel(const int* __restrict__ bsum,
                             int* __restrict__ boff, int nb)
{
    if (threadIdx.x == 0) {
        int run = 0;
        for (int i = 0; i < nb; ++i) { boff[i] = run; run += bsum[i]; }
    }
}

__global__ __launch_bounds__(256) void scan3_kernel(
    const int* __restrict__ incl, const int* __restrict__ deg,
    const int* __restrict__ boff, int* __restrict__ start,
    int* __restrict__ cursor, int n)
{
    int t = blockIdx.x * 256 + threadIdx.x;
    if (t < n) {
        int st = boff[t >> 10] + incl[t] - deg[t];   // exclusive
        start[t] = st;
        cursor[t] = st;
    }
}

__global__ __launch_bounds__(256) void fill_kernel(
    const int* __restrict__ src, const int* __restrict__ dst,
    int* __restrict__ cursor, int* __restrict__ eid, int E)
{
    int t = blockIdx.x * 256 + threadIdx.x;
    if (t < E) {
        int p = atomicAdd(&cursor[dst[t]], 1);
        eid[p] = src[t];
    }
}

// ---------------- gather aggregation: agg[v] = mean_{s in N(v)} x[s] ----------------
__global__ __launch_bounds__(256) void aggregate_kernel(
    const float* __restrict__ xin, const int* __restrict__ eid,
    const int* __restrict__ start, const int* __restrict__ deg,
    float* __restrict__ agg, int n)
{
    int w = (blockIdx.x * 256 + threadIdx.x) >> 6;   // one wave per node
    int l = threadIdx.x & 63;                        // lane: 2 consecutive floats
    if (w >= n) return;
    const int beg = start[w];
    const int c   = deg[w];
    const float2* x2 = reinterpret_cast<const float2*>(xin);

    float2 acc0 = make_float2(0.f, 0.f);
    float2 acc1 = make_float2(0.f, 0.f);
    int off = beg, rem = c;
    while (rem > 0) {
        int m = rem < 64 ? rem : 64;
        int id = (l < m) ? eid[off + l] : 0;
        int j = 0;
        for (; j + 1 < m; j += 2) {
            int s0 = __shfl(id, j);
            int s1 = __shfl(id, j + 1);
            float2 v0 = x2[(size_t)s0 * 64 + l];
            float2 v1 = x2[(size_t)s1 * 64 + l];
            acc0.x += v0.x; acc0.y += v0.y;
            acc1.x += v1.x; acc1.y += v1.y;
        }
        if (j < m) {
            int s0 = __shfl(id, j);
            float2 v0 = x2[(size_t)s0 * 64 + l];
            acc0.x += v0.x; acc0.y += v0.y;
        }
        off += m; rem -= m;
    }
    float inv = 1.0f / fmaxf((float)c, 1.0f);
    float2 o = make_float2((acc0.x + acc1.x) * inv, (acc0.y + acc1.y) * inv);
    reinterpret_cast<float2*>(agg)[(size_t)w * 64 + l] = o;
}

// ---------------- fused: y = agg@Wl + x@Wr + bl ; skip = relu(x@sw1+sb1)@sw2+sb2
//                  plus column sum / sumsq of y for BatchNorm -----------------------
// NOTE: `skip` may alias `agg` (agg is fully consumed into LDS before any skip write;
// blocks only touch their own row range) -> no __restrict__ on those two.
__global__ __launch_bounds__(256) void fused_gemm_kernel(
    const float* __restrict__ xin, const float* agg,
    const float* __restrict__ Wl, const float* __restrict__ bl,
    const float* __restrict__ Wr,
    const float* __restrict__ sw1, const float* __restrict__ sb1,
    const float* __restrict__ sw2, const float* __restrict__ sb2,
    float* __restrict__ y, float* skip,
    float* __restrict__ colsum, float* __restrict__ colsq, int n)
{
    __shared__ float xs[TILE_R][F];    // 32 KB
    __shared__ float as_[TILE_R][F];   // 32 KB (reused as h buffer in phase 3/4)
    const int tid = threadIdx.x;
    const int r0 = blockIdx.x * TILE_R;

    // ---- stage x tile and agg tile into LDS ----
    for (int i = tid; i < TILE_R * (F / 4); i += 256) {
        int r = i >> 5;        // /32 float4 per row
        int c4 = i & 31;
        int row = r0 + r;
        float4 v = make_float4(0.f, 0.f, 0.f, 0.f);
        float4 a = make_float4(0.f, 0.f, 0.f, 0.f);
        if (row < n) {
            v = reinterpret_cast<const float4*>(xin)[row * 32 + c4];
            a = reinterpret_cast<const float4*>(agg)[row * 32 + c4];
        }
        reinterpret_cast<float4*>(&xs[r][0])[c4] = v;
        reinterpret_cast<float4*>(&as_[r][0])[c4] = a;
    }
    __syncthreads();

    // ---- phase 2: y tile. thread -> col j, half rh; 32 rows each ----
    const int j = tid & 127;
    const int rh = tid >> 7;       // 0..1
    const int rbase = rh * 32;
    float acc[32];
#pragma unroll
    for (int r = 0; r < 32; ++r) acc[r] = 0.f;
    for (int k = 0; k < F; k += 4) {
        float wl0 = Wl[(k + 0) * F + j], wl1 = Wl[(k + 1) * F + j],
              wl2 = Wl[(k + 2) * F + j], wl3 = Wl[(k + 3) * F + j];
        float wr0 = Wr[(k + 0) * F + j], wr1 = Wr[(k + 1) * F + j],
              wr2 = Wr[(k + 2) * F + j], wr3 = Wr[(k + 3) * F + j];
#pragma unroll
        for (int r = 0; r < 32; ++r) {
            const float4 xa = *reinterpret_cast<const float4*>(&xs[rbase + r][k]);
            const float4 aa = *reinterpret_cast<const float4*>(&as_[rbase + r][k]);
            acc[r] += aa.x * wl0 + aa.y * wl1 + aa.z * wl2 + aa.w * wl3
                    + xa.x * wr0 + xa.y * wr1 + xa.z * wr2 + xa.w * wr3;
        }
    }
    {
        const float bias = bl[j];
        float psum = 0.f, psq = 0.f;
#pragma unroll
        for (int r = 0; r < 32; ++r) {
            int row = r0 + rbase + r;
            if (row < n) {
                float v = acc[r] + bias;
                y[(size_t)row * F + j] = v;
                psum += v; psq += v * v;
            }
        }
        unsafeAtomicAdd(colsum + j, psum);
        unsafeAtomicAdd(colsq + j, psq);
    }

    // ---- phase 3: h = relu(x@sw1 + sb1), [TILE_R][FH] ----
    const int jh = tid & 63;
    const int rq = tid >> 6;       // 0..3
    const int rb2 = rq * 16;
    float hacc[16];
#pragma unroll
    for (int r = 0; r < 16; ++r) hacc[r] = 0.f;
    for (int k = 0; k < F; k += 4) {
        float w0 = sw1[(k + 0) * FH + jh], w1 = sw1[(k + 1) * FH + jh],
              w2 = sw1[(k + 2) * FH + jh], w3 = sw1[(k + 3) * FH + jh];
#pragma unroll
        for (int r = 0; r < 16; ++r) {
            const float4 xa = *reinterpret_cast<const float4*>(&xs[rb2 + r][k]);
            hacc[r] += xa.x * w0 + xa.y * w1 + xa.z * w2 + xa.w * w3;
        }
    }
    const float hb = sb1[jh];
    __syncthreads();               // all phase-2/3 reads of as_ complete
    float* hs = &as_[0][0];        // reuse as h[TILE_R][FH]
#pragma unroll
    for (int r = 0; r < 16; ++r)
        hs[(rb2 + r) * FH + jh] = fmaxf(hacc[r] + hb, 0.f);
    __syncthreads();

    // ---- phase 4: skip = h @ sw2 + sb2 ----
    float sacc[32];
#pragma unroll
    for (int r = 0; r < 32; ++r) sacc[r] = 0.f;
    for (int k = 0; k < FH; k += 4) {
        float w0 = sw2[(k + 0) * F + j], w1 = sw2[(k + 1) * F + j],
              w2 = sw2[(k + 2) * F + j], w3 = sw2[(k + 3) * F + j];
#pragma unroll
        for (int r = 0; r < 32; ++r) {
            const float4 ha = *reinterpret_cast<const float4*>(&hs[(rbase + r) * FH + k]);
            sacc[r] += ha.x * w0 + ha.y * w1 + ha.z * w2 + ha.w * w3;
        }
    }
    const float sb = sb2[j];
#pragma unroll
    for (int r = 0; r < 32; ++r) {
        int row = r0 + rbase + r;
        if (row < n) skip[(size_t)row * F + j] = sacc[r] + sb;
    }
}

// ---------------- BN stats -> scale/shift ----------------
__global__ void bn_finalize_kernel(const float* __restrict__ colsum,
                                   const float* __restrict__ colsq,
                                   const float* __restrict__ g,
                                   const float* __restrict__ beta,
                                   float* __restrict__ scale,
                                   float* __restrict__ shift, float invn)
{
    int j = threadIdx.x;
    float mu = colsum[j] * invn;
    float var = colsq[j] * invn - mu * mu;
    float rs = rsqrtf(var + EPS);
    float sc = rs * g[j];
    scale[j] = sc;
    shift[j] = beta[j] - mu * sc;
}

// ---------------- out = relu(y*scale + shift + skip) ----------------
__global__ __launch_bounds__(256) void apply_kernel(
    const float* __restrict__ y, const float* __restrict__ skip,
    const float* __restrict__ scale, const float* __restrict__ shift,
    float* __restrict__ out, int n4)
{
    int t = blockIdx.x * 256 + threadIdx.x;
    if (t >= n4) return;
    int j4 = t & 31;
    float4 v = reinterpret_cast<const float4*>(y)[t];
    float4 s = reinterpret_cast<const float4*>(skip)[t];
    float4 sc = reinterpret_cast<const float4*>(scale)[j4];
    float4 sh = reinterpret_cast<const float4*>(shift)[j4];
    float4 o;
    o.x = fmaxf(v.x * sc.x + sh.x + s.x, 0.f);
    o.y = fmaxf(v.y * sc.y + sh.y + s.y, 0.f);
    o.z = fmaxf(v.z * sc.z + sh.z + s.z, 0.f);
    o.w = fmaxf(v.w * sc.w + sh.w + s.w, 0.f);
    reinterpret_cast<float4*>(out)[t] = o;
}

extern "C" void kernel_launch(void* const* d_in, const int* in_sizes, int n_in,
                              void* d_out, int out_size, void* d_ws, size_t ws_size,
                              hipStream_t stream)
{
    const float* x    = (const float*)d_in[0];
    const int*   ei   = (const int*)d_in[1];
    const float* Wl1  = (const float*)d_in[2];
    const float* bl1  = (const float*)d_in[3];
    const float* Wr1  = (const float*)d_in[4];
    const float* Wl2  = (const float*)d_in[5];
    const float* bl2  = (const float*)d_in[6];
    const float* Wr2  = (const float*)d_in[7];
    const float* s1w1 = (const float*)d_in[8];
    const float* s1b1 = (const float*)d_in[9];
    const float* s1w2 = (const float*)d_in[10];
    const float* s1b2 = (const float*)d_in[11];
    const float* s2w1 = (const float*)d_in[12];
    const float* s2b1 = (const float*)d_in[13];
    const float* s2w2 = (const float*)d_in[14];
    const float* s2b2 = (const float*)d_in[15];
    const float* g1   = (const float*)d_in[16];
    const float* be1  = (const float*)d_in[17];
    const float* g2   = (const float*)d_in[18];
    const float* be2  = (const float*)d_in[19];

    const int n = in_sizes[0] / F;       // 100000
    const int E = in_sizes[1] / 2;       // 1600000
    const int* src = ei;
    const int* dst = ei + E;

    // ---- workspace carve-up ----
    float* ws = (float*)d_ws;
    size_t off = 0;
    float* agg  = ws + off; off += (size_t)n * F;   // also holds skip
    float* ybuf = ws + off; off += (size_t)n * F;
    float* x1   = ws + off; off += (size_t)n * F;
    float* csum = ws + off; off += F;
    float* csq  = ws + off; off += F;
    float* scl  = ws + off; off += F;
    float* shf  = ws + off; off += F;
    int* iws = (int*)(ws + off);
    size_t ioff = 0;
    int* deg    = iws + ioff; ioff += n;
    int* start  = iws + ioff; ioff += n;
    int* cursor = iws + ioff; ioff += n;
    int* incl   = iws + ioff; ioff += n;
    int* bsum   = iws + ioff; ioff += 256;
    int* boff   = iws + ioff; ioff += 256;
    int* eid    = iws + ioff; ioff += E;

    const int eblocks = (E + 255) / 256;
    const int nb1024  = (n + 1023) / 1024;
    const int nblocks = (n + 255) / 256;
    const int ablocks = (n + 3) / 4;               // 1 wave per node, 4 waves/block
    const int gblocks = (n + TILE_R - 1) / TILE_R;
    const int n4 = n * (F / 4);
    const int apblocks = (n4 + 255) / 256;
    const float invn = 1.0f / (float)n;

    // ---- CSR build (shared by both layers) ----
    hipMemsetAsync(deg, 0, (size_t)n * sizeof(int), stream);
    deg_kernel<<<eblocks, 256, 0, stream>>>(dst, deg, E);
    scan1_kernel<<<nb1024, 1024, 0, stream>>>(deg, incl, bsum, n);
    scan2_kernel<<<1, 64, 0, stream>>>(bsum, boff, nb1024);
    scan3_kernel<<<nblocks, 256, 0, stream>>>(incl, deg, boff, start, cursor, n);
    fill_kernel<<<eblocks, 256, 0, stream>>>(src, dst, cursor, eid, E);

    // ---- layer 1 ----
    hipMemsetAsync(csum, 0, 2 * F * sizeof(float), stream);   // csum + csq
    aggregate_kernel<<<ablocks, 256, 0, stream>>>(x, eid, start, deg, agg, n);
    fused_gemm_kernel<<<gblocks, 256, 0, stream>>>(x, agg, Wl1, bl1, Wr1,
        s1w1, s1b1, s1w2, s1b2, ybuf, agg /*skip*/, csum, csq, n);
    bn_finalize_kernel<<<1, F, 0, stream>>>(csum, csq, g1, be1, scl, shf, invn);
    apply_kernel<<<apblocks, 256, 0, stream>>>(ybuf, agg /*skip*/, scl, shf, x1, n4);

    // ---- layer 2 ----
    hipMemsetAsync(csum, 0, 2 * F * sizeof(float), stream);
    aggregate_kernel<<<ablocks, 256, 0, stream>>>(x1, eid, start, deg, agg, n);
    fused_gemm_kernel<<<gblocks, 256, 0, stream>>>(x1, agg, Wl2, bl2, Wr2,
        s2w1, s2b1, s2w2, s2b2, ybuf, agg /*skip*/, csum, csq, n);
    bn_finalize_kernel<<<1, F, 0, stream>>>(csum, csq, g2, be2, scl, shf, invn);
    apply_kernel<<<apblocks, 256, 0, stream>>>(ybuf, agg /*skip*/, scl, shf, (float*)d_out, n4);
}

// Round 3
// 743.087 us; speedup vs baseline: 8.5961x; 1.7774x over previous
//
#include <hip/hip_runtime.h>

// GraphSAGE round 3: CSR gather aggregation + bf16-MFMA fused GEMMs.
//
// GEMMs run on v_mfma_f32_16x16x32_bf16 (fp32 accumulate). Weights are
// pre-converted once per call into bf16 *fragment-order* arrays; A-tiles are
// staged into LDS in fragment order (conflict-free ds_read_b128).

#define F   128
#define FH  64
#define EPS 1e-5f

typedef __attribute__((ext_vector_type(8))) short short8v;
typedef __attribute__((ext_vector_type(4))) short short4v;
typedef __attribute__((ext_vector_type(4))) float floatx4;

__device__ inline unsigned short f2bf(float f) {
    unsigned u = __builtin_bit_cast(unsigned, f);
    u += 0x7fff + ((u >> 16) & 1);          // round-to-nearest-even
    return (unsigned short)(u >> 16);
}

// ---------------- CSR build ----------------
__global__ __launch_bounds__(256) void deg_kernel(
    const int* __restrict__ dst, int* __restrict__ deg, int E)
{
    int t = blockIdx.x * 256 + threadIdx.x;
    if (t < E) atomicAdd(&deg[dst[t]], 1);
}

__global__ __launch_bounds__(1024) void scan1_kernel(
    const int* __restrict__ deg, int* __restrict__ incl,
    int* __restrict__ bsum, int n)
{
    __shared__ int s[1024];
    int t = threadIdx.x;
    int idx = blockIdx.x * 1024 + t;
    int v = (idx < n) ? deg[idx] : 0;
    s[t] = v;
    __syncthreads();
    for (int o = 1; o < 1024; o <<= 1) {
        int a = (t >= o) ? s[t - o] : 0;
        __syncthreads();
        s[t] += a;
        __syncthreads();
    }
    if (idx < n) incl[idx] = s[t];
    if (t == 1023) bsum[blockIdx.x] = s[t];
}

__global__ void scan2_kernel(const int* __restrict__ bsum,
                             int* __restrict__ boff, int nb)
{
    if (threadIdx.x == 0) {
        int run = 0;
        for (int i = 0; i < nb; ++i) { boff[i] = run; run += bsum[i]; }
    }
}

__global__ __launch_bounds__(256) void scan3_kernel(
    const int* __restrict__ incl, const int* __restrict__ deg,
    const int* __restrict__ boff, int* __restrict__ start,
    int* __restrict__ cursor, int n)
{
    int t = blockIdx.x * 256 + threadIdx.x;
    if (t < n) {
        int st = boff[t >> 10] + incl[t] - deg[t];
        start[t] = st;
        cursor[t] = st;
    }
}

__global__ __launch_bounds__(256) void fill_kernel(
    const int* __restrict__ src, const int* __restrict__ dst,
    int* __restrict__ cursor, int* __restrict__ eid, int E)
{
    int t = blockIdx.x * 256 + threadIdx.x;
    if (t < E) {
        int p = atomicAdd(&cursor[dst[t]], 1);
        eid[p] = src[t];
    }
}

// ---------------- gather aggregation: agg[v] = mean_{s in N(v)} x[s] ----------------
__global__ __launch_bounds__(256) void aggregate_kernel(
    const float* __restrict__ xin, const int* __restrict__ eid,
    const int* __restrict__ start, const int* __restrict__ deg,
    float* __restrict__ agg, int n)
{
    int w = (blockIdx.x * 256 + threadIdx.x) >> 6;
    int l = threadIdx.x & 63;
    if (w >= n) return;
    const int beg = start[w];
    const int c   = deg[w];
    const float2* x2 = reinterpret_cast<const float2*>(xin);

    float2 acc0 = make_float2(0.f, 0.f);
    float2 acc1 = make_float2(0.f, 0.f);
    int off = beg, rem = c;
    while (rem > 0) {
        int m = rem < 64 ? rem : 64;
        int id = (l < m) ? eid[off + l] : 0;
        int j = 0;
        for (; j + 1 < m; j += 2) {
            int s0 = __shfl(id, j);
            int s1 = __shfl(id, j + 1);
            float2 v0 = x2[(size_t)s0 * 64 + l];
            float2 v1 = x2[(size_t)s1 * 64 + l];
            acc0.x += v0.x; acc0.y += v0.y;
            acc1.x += v1.x; acc1.y += v1.y;
        }
        if (j < m) {
            int s0 = __shfl(id, j);
            float2 v0 = x2[(size_t)s0 * 64 + l];
            acc0.x += v0.x; acc0.y += v0.y;
        }
        off += m; rem -= m;
    }
    float inv = 1.0f / fmaxf((float)c, 1.0f);
    float2 o = make_float2((acc0.x + acc1.x) * inv, (acc0.y + acc1.y) * inv);
    reinterpret_cast<float2*>(agg)[(size_t)w * 64 + l] = o;
}

// ---------------- weight prep: fp32 [K][N] -> bf16 fragment order ----------------
// frag index for W[k][c]: ct=c/16, ks=k/32, lane=(c%16)+16*((k%32)/8), j=k%8
// flat: ((ct*(K/32)+ks)*64 + lane)*8 + j
__global__ __launch_bounds__(256) void prep_w_kernel(
    const float* __restrict__ src, unsigned short* __restrict__ dstf, int K, int N)
{
    int t = blockIdx.x * 256 + threadIdx.x;
    if (t >= K * N) return;
    int k = t / N, c = t % N;
    int ct = c >> 4, ks = k >> 5;
    int lane = (c & 15) + (((k & 31) >> 3) << 4);
    int j = k & 7;
    dstf[((ct * (K >> 5) + ks) * 64 + lane) * 8 + j] = f2bf(src[t]);
}

// ---------------- fused MFMA GEMM ----------------
// y = agg@Wl + x@Wr + bl  (+ BN column sum/sumsq)
// skip = relu(x@sw1 + sb1) @ sw2 + sb2        (skip may alias agg)
__global__ __launch_bounds__(256, 2) void fused_gemm_mfma(
    const float* __restrict__ xin, const float* agg,
    const unsigned short* __restrict__ wlf, const unsigned short* __restrict__ wrf,
    const unsigned short* __restrict__ whf, const unsigned short* __restrict__ wsf,
    const float* __restrict__ bl, const float* __restrict__ sb1,
    const float* __restrict__ sb2,
    float* __restrict__ y, float* skip,
    float* __restrict__ colsum, float* __restrict__ colsq, int n)
{
    __shared__ unsigned short xsf[4 * 4 * 64 * 8];   // 16 KB, frag order
    __shared__ unsigned short asf[4 * 4 * 64 * 8];   // 16 KB, frag order
    __shared__ unsigned short hsm[64 * 88];          // 11.3 KB, row-major stride 88

    const int tid = threadIdx.x;
    const int r0 = blockIdx.x * 64;
    const int w = tid >> 6;         // wave 0..3: owns output cols [w*32, w*32+32)
    const int l = tid & 63;

    // ---- stage x & agg tiles into frag-order LDS (bf16) ----
    {
        const float4* x4 = reinterpret_cast<const float4*>(xin);
        const float4* a4 = reinterpret_cast<const float4*>(agg);
        for (int i = tid; i < 64 * 32; i += 256) {
            int r = i >> 5, c4 = i & 31;
            int row = r0 + r;
            float4 v = make_float4(0.f, 0.f, 0.f, 0.f);
            float4 a = make_float4(0.f, 0.f, 0.f, 0.f);
            if (row < n) { v = x4[row * 32 + c4]; a = a4[row * 32 + c4]; }
            int rt = r >> 4, ks = c4 >> 3;
            int lslot = (r & 15) + ((c4 & 7) >> 1 << 4);
            int j0 = (c4 & 1) * 4;
            int off = ((rt * 4 + ks) * 64 + lslot) * 8 + j0;
            short4v pv = { (short)f2bf(v.x), (short)f2bf(v.y), (short)f2bf(v.z), (short)f2bf(v.w) };
            short4v pa = { (short)f2bf(a.x), (short)f2bf(a.y), (short)f2bf(a.z), (short)f2bf(a.w) };
            *(short4v*)&xsf[off] = pv;
            *(short4v*)&asf[off] = pa;
        }
    }

    // ---- load register-resident B fragments ----
    const short8v* wl8 = (const short8v*)wlf;
    const short8v* wr8 = (const short8v*)wrf;
    const short8v* wh8 = (const short8v*)whf;
    const short8v* ws8 = (const short8v*)wsf;
    short8v bWl[2][4], bWr[2][4];
#pragma unroll
    for (int ct = 0; ct < 2; ++ct)
#pragma unroll
        for (int ks = 0; ks < 4; ++ks) {
            int idx = ((w * 2 + ct) * 4 + ks) * 64 + l;
            bWl[ct][ks] = wl8[idx];
            bWr[ct][ks] = wr8[idx];
        }
    short8v bh[4];
#pragma unroll
    for (int ks = 0; ks < 4; ++ks) bh[ks] = wh8[(w * 4 + ks) * 64 + l];
    short8v bs[2][2];
#pragma unroll
    for (int ct = 0; ct < 2; ++ct)
#pragma unroll
        for (int ks = 0; ks < 2; ++ks)
            bs[ct][ks] = ws8[((w * 2 + ct) * 2 + ks) * 64 + l];

    __syncthreads();

    const short8v* xs8 = (const short8v*)xsf;
    const short8v* as8 = (const short8v*)asf;
    const int col0 = w * 32 + (l & 15);
    const float bias0 = bl[col0], bias1 = bl[col0 + 16];

    // ---- phase Y ----
    float psum0 = 0.f, psq0 = 0.f, psum1 = 0.f, psq1 = 0.f;
#pragma unroll
    for (int rt = 0; rt < 4; ++rt) {
        floatx4 acc0 = {0.f, 0.f, 0.f, 0.f};
        floatx4 acc1 = {0.f, 0.f, 0.f, 0.f};
#pragma unroll
        for (int ks = 0; ks < 4; ++ks) {
            short8v ax = xs8[(rt * 4 + ks) * 64 + l];
            short8v aa = as8[(rt * 4 + ks) * 64 + l];
            acc0 = __builtin_amdgcn_mfma_f32_16x16x32_bf16(aa, bWl[0][ks], acc0, 0, 0, 0);
            acc0 = __builtin_amdgcn_mfma_f32_16x16x32_bf16(ax, bWr[0][ks], acc0, 0, 0, 0);
            acc1 = __builtin_amdgcn_mfma_f32_16x16x32_bf16(aa, bWl[1][ks], acc1, 0, 0, 0);
            acc1 = __builtin_amdgcn_mfma_f32_16x16x32_bf16(ax, bWr[1][ks], acc1, 0, 0, 0);
        }
        int rowb = r0 + rt * 16 + (l >> 4) * 4;
#pragma unroll
        for (int reg = 0; reg < 4; ++reg) {
            int row = rowb + reg;
            if (row < n) {
                float v0 = acc0[reg] + bias0;
                float v1 = acc1[reg] + bias1;
                y[(size_t)row * F + col0] = v0;
                y[(size_t)row * F + col0 + 16] = v1;
                psum0 += v0; psq0 += v0 * v0;
                psum1 += v1; psq1 += v1 * v1;
            }
        }
    }
    // reduce over the 4 row-quads holding the same column
    psum0 += __shfl_xor(psum0, 16); psum0 += __shfl_xor(psum0, 32);
    psq0  += __shfl_xor(psq0, 16);  psq0  += __shfl_xor(psq0, 32);
    psum1 += __shfl_xor(psum1, 16); psum1 += __shfl_xor(psum1, 32);
    psq1  += __shfl_xor(psq1, 16);  psq1  += __shfl_xor(psq1, 32);
    if (l < 16) {
        unsafeAtomicAdd(&colsum[col0], psum0);
        unsafeAtomicAdd(&colsq[col0], psq0);
        unsafeAtomicAdd(&colsum[col0 + 16], psum1);
        unsafeAtomicAdd(&colsq[col0 + 16], psq1);
    }

    // ---- phase H: h = relu(x@sw1 + sb1) -> LDS bf16 [64][88] ----
    const int hcol = w * 16 + (l & 15);
    const float hbias = sb1[hcol];
#pragma unroll
    for (int rt = 0; rt < 4; ++rt) {
        floatx4 hacc = {0.f, 0.f, 0.f, 0.f};
#pragma unroll
        for (int ks = 0; ks < 4; ++ks) {
            short8v ax = xs8[(rt * 4 + ks) * 64 + l];
            hacc = __builtin_amdgcn_mfma_f32_16x16x32_bf16(ax, bh[ks], hacc, 0, 0, 0);
        }
        int rowb = rt * 16 + (l >> 4) * 4;
#pragma unroll
        for (int reg = 0; reg < 4; ++reg)
            hsm[(rowb + reg) * 88 + hcol] = f2bf(fmaxf(hacc[reg] + hbias, 0.f));
    }
    __syncthreads();

    // ---- phase S: skip = h @ sw2 + sb2 ----
    const float sbias0 = sb2[col0], sbias1 = sb2[col0 + 16];
#pragma unroll
    for (int rt = 0; rt < 4; ++rt) {
        floatx4 s0 = {0.f, 0.f, 0.f, 0.f};
        floatx4 s1 = {0.f, 0.f, 0.f, 0.f};
#pragma unroll
        for (int ks = 0; ks < 2; ++ks) {
            // A-frag of h: row = rt*16+(l&15), k = ks*32 + (l>>4)*8 + j
            short8v ah = *(const short8v*)&hsm[(rt * 16 + (l & 15)) * 88 + ks * 32 + (l >> 4) * 8];
            s0 = __builtin_amdgcn_mfma_f32_16x16x32_bf16(ah, bs[0][ks], s0, 0, 0, 0);
            s1 = __builtin_amdgcn_mfma_f32_16x16x32_bf16(ah, bs[1][ks], s1, 0, 0, 0);
        }
        int rowb = r0 + rt * 16 + (l >> 4) * 4;
#pragma unroll
        for (int reg = 0; reg < 4; ++reg) {
            int row = rowb + reg;
            if (row < n) {
                skip[(size_t)row * F + col0] = s0[reg] + sbias0;
                skip[(size_t)row * F + col0 + 16] = s1[reg] + sbias1;
            }
        }
    }
}

// ---------------- BN stats -> scale/shift ----------------
__global__ void bn_finalize_kernel(const float* __restrict__ colsum,
                                   const float* __restrict__ colsq,
                                   const float* __restrict__ g,
                                   const float* __restrict__ beta,
                                   float* __restrict__ scale,
                                   float* __restrict__ shift, float invn)
{
    int j = threadIdx.x;
    float mu = colsum[j] * invn;
    float var = colsq[j] * invn - mu * mu;
    float rs = rsqrtf(var + EPS);
    float sc = rs * g[j];
    scale[j] = sc;
    shift[j] = beta[j] - mu * sc;
}

// ---------------- out = relu(y*scale + shift + skip) ----------------
__global__ __launch_bounds__(256) void apply_kernel(
    const float* __restrict__ y, const float* __restrict__ skip,
    const float* __restrict__ scale, const float* __restrict__ shift,
    float* __restrict__ out, int n4)
{
    int t = blockIdx.x * 256 + threadIdx.x;
    if (t >= n4) return;
    int j4 = t & 31;
    float4 v = reinterpret_cast<const float4*>(y)[t];
    float4 s = reinterpret_cast<const float4*>(skip)[t];
    float4 sc = reinterpret_cast<const float4*>(scale)[j4];
    float4 sh = reinterpret_cast<const float4*>(shift)[j4];
    float4 o;
    o.x = fmaxf(v.x * sc.x + sh.x + s.x, 0.f);
    o.y = fmaxf(v.y * sc.y + sh.y + s.y, 0.f);
    o.z = fmaxf(v.z * sc.z + sh.z + s.z, 0.f);
    o.w = fmaxf(v.w * sc.w + sh.w + s.w, 0.f);
    reinterpret_cast<float4*>(out)[t] = o;
}

extern "C" void kernel_launch(void* const* d_in, const int* in_sizes, int n_in,
                              void* d_out, int out_size, void* d_ws, size_t ws_size,
                              hipStream_t stream)
{
    const float* x    = (const float*)d_in[0];
    const int*   ei   = (const int*)d_in[1];
    const float* Wl1  = (const float*)d_in[2];
    const float* bl1  = (const float*)d_in[3];
    const float* Wr1  = (const float*)d_in[4];
    const float* Wl2  = (const float*)d_in[5];
    const float* bl2  = (const float*)d_in[6];
    const float* Wr2  = (const float*)d_in[7];
    const float* s1w1 = (const float*)d_in[8];
    const float* s1b1 = (const float*)d_in[9];
    const float* s1w2 = (const float*)d_in[10];
    const float* s1b2 = (const float*)d_in[11];
    const float* s2w1 = (const float*)d_in[12];
    const float* s2b1 = (const float*)d_in[13];
    const float* s2w2 = (const float*)d_in[14];
    const float* s2b2 = (const float*)d_in[15];
    const float* g1   = (const float*)d_in[16];
    const float* be1  = (const float*)d_in[17];
    const float* g2   = (const float*)d_in[18];
    const float* be2  = (const float*)d_in[19];

    const int n = in_sizes[0] / F;       // 100000
    const int E = in_sizes[1] / 2;       // 1600000
    const int* src = ei;
    const int* dst = ei + E;

    // ---- workspace carve-up ----
    float* ws = (float*)d_ws;
    size_t off = 0;
    float* agg  = ws + off; off += (size_t)n * F;   // also holds skip
    float* ybuf = ws + off; off += (size_t)n * F;
    float* x1   = ws + off; off += (size_t)n * F;
    float* csum = ws + off; off += F;
    float* csq  = ws + off; off += F;
    float* scl  = ws + off; off += F;
    float* shf  = ws + off; off += F;
    // bf16 weight fragments
    unsigned short* wbf = (unsigned short*)(ws + off);
    size_t woff = 0;
    unsigned short* fWl1 = wbf + woff; woff += F * F;
    unsigned short* fWr1 = wbf + woff; woff += F * F;
    unsigned short* fWl2 = wbf + woff; woff += F * F;
    unsigned short* fWr2 = wbf + woff; woff += F * F;
    unsigned short* fs1w1 = wbf + woff; woff += F * FH;
    unsigned short* fs2w1 = wbf + woff; woff += F * FH;
    unsigned short* fs1w2 = wbf + woff; woff += FH * F;
    unsigned short* fs2w2 = wbf + woff; woff += FH * F;
    off += (woff + 1) / 2;
    int* iws = (int*)(ws + off);
    size_t ioff = 0;
    int* deg    = iws + ioff; ioff += n;
    int* start  = iws + ioff; ioff += n;
    int* cursor = iws + ioff; ioff += n;
    int* incl   = iws + ioff; ioff += n;
    int* bsum   = iws + ioff; ioff += 256;
    int* boff   = iws + ioff; ioff += 256;
    int* eid    = iws + ioff; ioff += E;

    const int eblocks = (E + 255) / 256;
    const int nb1024  = (n + 1023) / 1024;
    const int nblocks = (n + 255) / 256;
    const int ablocks = (n + 3) / 4;
    const int gblocks = (n + 63) / 64;
    const int n4 = n * (F / 4);
    const int apblocks = (n4 + 255) / 256;
    const float invn = 1.0f / (float)n;
    const int wb128 = (F * F + 255) / 256;
    const int wb64  = (F * FH + 255) / 256;

    // ---- CSR build ----
    hipMemsetAsync(deg, 0, (size_t)n * sizeof(int), stream);
    deg_kernel<<<eblocks, 256, 0, stream>>>(dst, deg, E);
    scan1_kernel<<<nb1024, 1024, 0, stream>>>(deg, incl, bsum, n);
    scan2_kernel<<<1, 64, 0, stream>>>(bsum, boff, nb1024);
    scan3_kernel<<<nblocks, 256, 0, stream>>>(incl, deg, boff, start, cursor, n);
    fill_kernel<<<eblocks, 256, 0, stream>>>(src, dst, cursor, eid, E);

    // ---- weight prep (bf16 frag order) ----
    prep_w_kernel<<<wb128, 256, 0, stream>>>(Wl1, fWl1, F, F);
    prep_w_kernel<<<wb128, 256, 0, stream>>>(Wr1, fWr1, F, F);
    prep_w_kernel<<<wb128, 256, 0, stream>>>(Wl2, fWl2, F, F);
    prep_w_kernel<<<wb128, 256, 0, stream>>>(Wr2, fWr2, F, F);
    prep_w_kernel<<<wb64, 256, 0, stream>>>(s1w1, fs1w1, F, FH);
    prep_w_kernel<<<wb64, 256, 0, stream>>>(s2w1, fs2w1, F, FH);
    prep_w_kernel<<<wb64, 256, 0, stream>>>(s1w2, fs1w2, FH, F);
    prep_w_kernel<<<wb64, 256, 0, stream>>>(s2w2, fs2w2, FH, F);

    // ---- layer 1 ----
    hipMemsetAsync(csum, 0, 2 * F * sizeof(float), stream);
    aggregate_kernel<<<ablocks, 256, 0, stream>>>(x, eid, start, deg, agg, n);
    fused_gemm_mfma<<<gblocks, 256, 0, stream>>>(x, agg, fWl1, fWr1, fs1w1, fs1w2,
        bl1, s1b1, s1b2, ybuf, agg /*skip*/, csum, csq, n);
    bn_finalize_kernel<<<1, F, 0, stream>>>(csum, csq, g1, be1, scl, shf, invn);
    apply_kernel<<<apblocks, 256, 0, stream>>>(ybuf, agg /*skip*/, scl, shf, x1, n4);

    // ---- layer 2 ----
    hipMemsetAsync(csum, 0, 2 * F * sizeof(float), stream);
    aggregate_kernel<<<ablocks, 256, 0, stream>>>(x1, eid, start, deg, agg, n);
    fused_gemm_mfma<<<gblocks, 256, 0, stream>>>(x1, agg, fWl2, fWr2, fs2w1, fs2w2,
        bl2, s2b1, s2b2, ybuf, agg /*skip*/, csum, csq, n);
    bn_finalize_kernel<<<1, F, 0, stream>>>(csum, csq, g2, be2, scl, shf, invn);
    apply_kernel<<<apblocks, 256, 0, stream>>>(ybuf, agg /*skip*/, scl, shf, (float*)d_out, n4);
}